// Round 13
// baseline (270.464 us; speedup 1.0000x reference)
//
#include <hip/hip_runtime.h>
#include <hip/hip_bf16.h>

#define SEQ_T 100
#define HID 20
#define EMB_D 50
#define VOCAB_N 50000
#define TABW 60          // tab row stride (floats) = 60 gate cols [z20|r20|h20]
#define NTILE 3125       // VOCAB_N/16
#define BBLK 200         // build_table blocks (x4 waves = 800 waves)

typedef short sh8 __attribute__((ext_vector_type(8)));   // 8 bf16 bit patterns
typedef float f4  __attribute__((ext_vector_type(4)));

// ws layout (float offsets). TOTAL = 4160*4 + 50000*60*4 = 12,016,640 B
// (rounds 7/8/11/12 proven-safe footprint).
#define OFF_U1T 0        // U1 transposed: U1T[j*20+k] = U1[k][j]  (1200)
#define OFF_W2T 1200
#define OFF_U2T 2400
#define OFF_B1  3600     // 120
#define OFF_B2  3720     // 120
#define OFF_WD  3840     // 300
#define OFF_BD  4140     // 15
#define OFF_TAB 4160     // 50000*60 floats

__device__ __forceinline__ float ldf(const void* p, int i, int isf) {
  return isf ? ((const float*)p)[i]
             : __bfloat162float(((const __hip_bfloat16*)p)[i]);
}
__device__ __forceinline__ short f2bf(float f) {   // RNE fp32->bf16 bits
  unsigned u = __float_as_uint(f);
  u += 0x7fffu + ((u >> 16) & 1u);
  return (short)(u >> 16);
}
__device__ __forceinline__ float rdl(float v, int l) {
  return __uint_as_float(__builtin_amdgcn_readlane(__float_as_uint(v), l));
}
// fp32 data read as u16 halfwords has uniform-random bf16-exponent fields
// (>=140 w.p. ~0.45 per low half); bf16 N(0,0.05) never exceeds ~125.
__device__ __forceinline__ int detect_isf(const void* emb) {
  uint4 dv = ((const uint4*)emb)[threadIdx.x & 63];
  int big = 0;
#pragma unroll
  for (int i = 0; i < 4; ++i) {
    unsigned w = ((const unsigned*)&dv)[i];
    big |= (((w >> 7) & 0xFF) >= 140) | (((w >> 23) & 0xFF) >= 140);
  }
  return (__ballot(big) != 0ull) ? 1 : 0;
}

// tab = emb @ W1 + bi1 on the matrix cores (M=50000, N=60->64, K=50->64).
// ROUND-13: grid-stride tiles (800 waves, ~4 tiles each); B-fragments built
// ONCE per block by wave 0 into LDS and ds_read_b128 per tile -- the old
// per-tile B rebuild (~64 scalar ldf+cvt per lane per tile) dominated the
// 55-65 us build phase. Block 0 also preps fp32/transposed weights in ws.
__global__ __launch_bounds__(256) void build_table(
    const void* __restrict__ emb, const void* __restrict__ W1,
    const void* __restrict__ b1,
    const void* __restrict__ U1, const void* __restrict__ W2,
    const void* __restrict__ U2, const void* __restrict__ b2,
    const void* __restrict__ Wd, const void* __restrict__ bd,
    float* __restrict__ ws)
{
  const int isf = detect_isf(emb);
  if (blockIdx.x == 0) {                     // fold: weight prep (fp32+T)
    const int t = threadIdx.x;
    for (int i = t; i < 1200; i += 256) {
      const int j = i / 20, k = i % 20;      // transposed layout
      ws[OFF_U1T + i] = ldf(U1, k * TABW + j, isf);
      ws[OFF_W2T + i] = ldf(W2, k * TABW + j, isf);
      ws[OFF_U2T + i] = ldf(U2, k * TABW + j, isf);
    }
    for (int i = t; i < 120; i += 256) {
      ws[OFF_B1 + i] = ldf(b1, i, isf);
      ws[OFF_B2 + i] = ldf(b2, i, isf);
    }
    for (int i = t; i < 300; i += 256) ws[OFF_WD + i] = ldf(Wd, i, isf);
    for (int i = t; i < 15;  i += 256) ws[OFF_BD + i] = ldf(bd, i, isf);
  }

  const int L = threadIdx.x & 63, q = L >> 4, c = L & 15;
  const int wid = blockIdx.x * 4 + (threadIdx.x >> 6);
  float* __restrict__ tab = ws + OFF_TAB;

  // ---- B-frags: built once per block into LDS (wave 0), b128-read later ----
  __shared__ int4 sB[64][8];                 // [lane][nt*2 + {B0,B1}], 8 KB
  if (threadIdx.x < 64) {
#pragma unroll
    for (int nt = 0; nt < 4; ++nt) {
      const int col = nt * 16 + c;
      sh8 B0, B1;
#pragma unroll
      for (int jj = 0; jj < 8; ++jj) {       // B[k=quad*8+j][n=lane&15]
        const int k0 = q * 8 + jj, k1 = 32 + q * 8 + jj;
        B0[jj] = (col < TABW) ? f2bf(ldf(W1, k0 * TABW + col, isf)) : (short)0;
        B1[jj] = (col < TABW && k1 < EMB_D)
                     ? f2bf(ldf(W1, k1 * TABW + col, isf)) : (short)0;
      }
      sB[L][nt * 2]     = *(const int4*)&B0;
      sB[L][nt * 2 + 1] = *(const int4*)&B1;
    }
  }
  // bias per n-tile (wave-local registers)
  float bi[4];
#pragma unroll
  for (int nt = 0; nt < 4; ++nt) {
    const int col = nt * 16 + c;
    bi[nt] = (col < TABW) ? ldf(b1, col, isf) : 0.f;
  }
  __syncthreads();

  for (int tile = wid; tile < NTILE; tile += BBLK * 4) {
    const int v0 = tile * 16;

    // A-frags: A[m=lane&15][k=quad*8+j]; row v0+c; k-tiles 0..31 / 32..63
    sh8 A0, A1;
#pragma unroll
    for (int jj = 0; jj < 8; ++jj) { A0[jj] = 0; A1[jj] = 0; }
    if (!isf) {
      const unsigned short* eb = (const unsigned short*)emb;
      const size_t rb = (size_t)(v0 + c) * EMB_D;
#pragma unroll
      for (int i = 0; i < 4; ++i) {          // dword loads: rows are 100 B
        unsigned d = *(const unsigned*)(eb + rb + q * 8 + 2 * i);
        A0[2 * i] = (short)(d & 0xffff); A0[2 * i + 1] = (short)(d >> 16);
      }
      const int k1b = 32 + q * 8;
#pragma unroll
      for (int i = 0; i < 4; ++i) {
        const int k = k1b + 2 * i;
        if (k + 1 < EMB_D) {                 // q=0,1 full; q=2 partial
          unsigned d = *(const unsigned*)(eb + rb + k);
          A1[2 * i] = (short)(d & 0xffff); A1[2 * i + 1] = (short)(d >> 16);
        }
      }
    } else {
      const float* ef = (const float*)emb;
      const size_t rb = (size_t)(v0 + c) * EMB_D;
#pragma unroll
      for (int jj = 0; jj < 8; ++jj) {
        const int k0 = q * 8 + jj, k1 = 32 + q * 8 + jj;
        A0[jj] = f2bf(ef[rb + k0]);
        A1[jj] = (k1 < EMB_D) ? f2bf(ef[rb + k1]) : (short)0;
      }
    }

#pragma unroll
    for (int nt = 0; nt < 4; ++nt) {
      int4 b0i = sB[L][nt * 2], b1i = sB[L][nt * 2 + 1];
      sh8 B0 = *(const sh8*)&b0i, B1 = *(const sh8*)&b1i;
      const int col = nt * 16 + c;
      f4 acc = { bi[nt], bi[nt], bi[nt], bi[nt] };
      acc = __builtin_amdgcn_mfma_f32_16x16x32_bf16(A0, B0, acc, 0, 0, 0);
      acc = __builtin_amdgcn_mfma_f32_16x16x32_bf16(A1, B1, acc, 0, 0, 0);
      if (col < TABW) {                      // C/D: col=lane&15, row=q*4+reg
#pragma unroll
        for (int r = 0; r < 4; ++r)
          tab[(size_t)(v0 + q * 4 + r) * TABW + col] = acc[r];
      }
    }
  }
}

// ONE batch element per wave; ENTIRE 100-step GRU loop in inline asm with
// explicit registers (C++ RA caps at ~44 VGPR, rounds 3-8). TRANS hazards
// fenced with s_nop (round-11 fix). Matvecs: v_pk_fma_f32 over k-pairs
// (round-12, verified). UNCHANGED from round 12.
__global__ __launch_bounds__(64, 4) void gru_main(
    const int* __restrict__ x, const float* __restrict__ ws,
    const void* __restrict__ emb, void* __restrict__ out)
{
  const int isf = detect_isf(emb);   // output dtype only
  const int j = threadIdx.x & 63;
  const int e = blockIdx.x;
  const int jc = j < TABW ? j : 0;

  const int* xr = x + (size_t)e * SEQ_T;
  const float* tab = ws + OFF_TAB;
  const int o1 = jc * 80;                    // 20 floats * 4 B per column
  const int o2 = 4800 + jc * 80;             // OFF_W2T * 4
  const int o3 = 9600 + jc * 80;             // OFF_U2T * 4
  const int jc4 = jc * 4;                    // byte offset of col jc in a row
  const int a1 = ((j - 20) & 63) * 4;        // bpermute addr: r -> h-lanes
  const int a2 = ((j + 40) & 63) * 4;        // bpermute addr: hc -> z-lanes
  const float br1 = ws[OFF_B1 + 60 + jc];
  const float bi2 = ws[OFF_B2 + jc];
  const float br2 = ws[OFF_B2 + 60 + jc];
  float h2out;

#define L1FMA(K, V) "v_readlane_b32 s" #K ", v70, " #V "\n\t"
#define L2FMA(K, V) "v_readlane_b32 s" #K ", v71, " #V "\n\t"
  asm volatile(
    // ---- weights: 60 floats -> v10..v69 (k-contiguous per column) ----
    "global_load_dwordx4 v[10:13], %[o1], %[wsp] offset:0\n\t"
    "global_load_dwordx4 v[14:17], %[o1], %[wsp] offset:16\n\t"
    "global_load_dwordx4 v[18:21], %[o1], %[wsp] offset:32\n\t"
    "global_load_dwordx4 v[22:25], %[o1], %[wsp] offset:48\n\t"
    "global_load_dwordx4 v[26:29], %[o1], %[wsp] offset:64\n\t"
    "global_load_dwordx4 v[30:33], %[o2], %[wsp] offset:0\n\t"
    "global_load_dwordx4 v[34:37], %[o2], %[wsp] offset:16\n\t"
    "global_load_dwordx4 v[38:41], %[o2], %[wsp] offset:32\n\t"
    "global_load_dwordx4 v[42:45], %[o2], %[wsp] offset:48\n\t"
    "global_load_dwordx4 v[46:49], %[o2], %[wsp] offset:64\n\t"
    "global_load_dwordx4 v[50:53], %[o3], %[wsp] offset:0\n\t"
    "global_load_dwordx4 v[54:57], %[o3], %[wsp] offset:16\n\t"
    "global_load_dwordx4 v[58:61], %[o3], %[wsp] offset:32\n\t"
    "global_load_dwordx4 v[62:65], %[o3], %[wsp] offset:48\n\t"
    "global_load_dwordx4 v[66:69], %[o3], %[wsp] offset:64\n\t"
    // ---- h state zero: h1 = s20..s39 (s[20+k]=h1[k]), h2 = s40..s59 ----
    "s_mov_b64 s[20:21], 0\n\ts_mov_b64 s[22:23], 0\n\t"
    "s_mov_b64 s[24:25], 0\n\ts_mov_b64 s[26:27], 0\n\t"
    "s_mov_b64 s[28:29], 0\n\ts_mov_b64 s[30:31], 0\n\t"
    "s_mov_b64 s[32:33], 0\n\ts_mov_b64 s[34:35], 0\n\t"
    "s_mov_b64 s[36:37], 0\n\ts_mov_b64 s[38:39], 0\n\t"
    "s_mov_b64 s[40:41], 0\n\ts_mov_b64 s[42:43], 0\n\t"
    "s_mov_b64 s[44:45], 0\n\ts_mov_b64 s[46:47], 0\n\t"
    "s_mov_b64 s[48:49], 0\n\ts_mov_b64 s[50:51], 0\n\t"
    "s_mov_b64 s[52:53], 0\n\ts_mov_b64 s[54:55], 0\n\t"
    "s_mov_b64 s[56:57], 0\n\ts_mov_b64 s[58:59], 0\n\t"
    "v_mov_b32 v70, 0\n\t"
    "v_mov_b32 v71, 0\n\t"
    // ---- prime mx(0), mx(1); idx(2) in flight. row stride 240 B ----
    "s_load_dword s65, %[xp], 0x0\n\t"
    "s_load_dword s66, %[xp], 0x4\n\t"
    "s_waitcnt lgkmcnt(0)\n\t"
    "s_mul_i32 s65, s65, 240\n\t"
    "s_mul_i32 s66, s66, 240\n\t"
    "v_add_u32 v80, s65, %[jc4]\n\t"
    "global_load_dword v72, v80, %[tabp]\n\t"
    "v_add_u32 v80, s66, %[jc4]\n\t"
    "global_load_dword v73, v80, %[tabp]\n\t"
    "s_load_dword s65, %[xp], 0x8\n\t"
    "s_movk_i32 s64, 0xc\n\t"
    "s_movk_i32 s67, 0x64\n\t"
    "s_waitcnt vmcnt(0)\n\t"
    "0:\n\t"
    // ---- layer 1: mh = h1 @ U1 + br1 (k-pair pk_fma, even/odd split) ----
    "v_mov_b32 v74, %[br1]\n\t"
    "v_mov_b32 v75, 0\n\t"
    "v_pk_fma_f32 v[74:75], s[20:21], v[10:11], v[74:75]\n\t"
    "v_pk_fma_f32 v[74:75], s[22:23], v[12:13], v[74:75]\n\t"
    "v_pk_fma_f32 v[74:75], s[24:25], v[14:15], v[74:75]\n\t"
    "v_pk_fma_f32 v[74:75], s[26:27], v[16:17], v[74:75]\n\t"
    "v_pk_fma_f32 v[74:75], s[28:29], v[18:19], v[74:75]\n\t"
    "v_pk_fma_f32 v[74:75], s[30:31], v[20:21], v[74:75]\n\t"
    "v_pk_fma_f32 v[74:75], s[32:33], v[22:23], v[74:75]\n\t"
    "v_pk_fma_f32 v[74:75], s[34:35], v[24:25], v[74:75]\n\t"
    "v_pk_fma_f32 v[74:75], s[36:37], v[26:27], v[74:75]\n\t"
    "v_pk_fma_f32 v[74:75], s[38:39], v[28:29], v[74:75]\n\t"
    "v_add_f32 v74, v74, v75\n\t"          // mh = even + odd partial
    // g = sigmoid(mx + mh)   (z in lanes 0..19, r in 20..39)
    "v_add_f32 v75, v72, v74\n\t"
    "v_mul_f32 v75, 0xbfb8aa3b, v75\n\t"   // * -log2(e)
    "v_exp_f32 v75, v75\n\t"
    "s_nop 1\n\t"                          // TRANS result hazard fence
    "v_add_f32 v75, 1.0, v75\n\t"
    "v_rcp_f32 v75, v75\n\t"
    "s_nop 1\n\t"                          // TRANS result hazard fence
    "ds_bpermute_b32 v76, %[a1], v75\n\t"  // rr: h-lanes pull r
    "s_waitcnt lgkmcnt(0)\n\t"
    "v_fma_f32 v77, v76, v74, v72\n\t"     // hp = rr*mh + mx
    "v_mul_f32 v77, 0x4038aa3b, v77\n\t"   // * 2*log2(e)
    "v_exp_f32 v77, v77\n\t"
    "s_nop 1\n\t"                          // TRANS result hazard fence
    "v_add_f32 v77, 1.0, v77\n\t"
    "v_rcp_f32 v77, v77\n\t"
    "s_nop 1\n\t"                          // TRANS result hazard fence
    "v_fma_f32 v77, -2.0, v77, 1.0\n\t"    // hc = tanh(hp)
    "ds_bpermute_b32 v76, %[a2], v77\n\t"  // hv: z-lanes pull hc
    "s_waitcnt lgkmcnt(0)\n\t"
    "v_sub_f32 v78, v70, v76\n\t"
    "v_fma_f32 v70, v75, v78, v76\n\t"     // h1 = g*(h1-hv)+hv
    "s_nop 1\n\t"                          // VALU->readlane fence
    L1FMA(20,0) L1FMA(21,1) L1FMA(22,2) L1FMA(23,3) L1FMA(24,4)
    L1FMA(25,5) L1FMA(26,6) L1FMA(27,7) L1FMA(28,8) L1FMA(29,9)
    L1FMA(30,10) L1FMA(31,11) L1FMA(32,12) L1FMA(33,13) L1FMA(34,14)
    L1FMA(35,15) L1FMA(36,16) L1FMA(37,17) L1FMA(38,18) L1FMA(39,19)
    // ---- rotate mx pipeline, prefetch mx(t+2), idx(t+3) ----
    "s_mul_i32 s66, s65, 240\n\t"
    "v_add_u32 v80, s66, %[jc4]\n\t"
    "s_waitcnt vmcnt(0)\n\t"
    "v_mov_b32 v72, v73\n\t"
    "global_load_dword v73, v80, %[tabp]\n\t"
    "s_min_u32 s64, s64, 396\n\t"
    "s_load_dword s65, %[xp], s64\n\t"
    "s_add_u32 s64, s64, 4\n\t"
    // ---- layer 2: m2 = h1 @ W2 + bi2 ; n2 = h2 @ U2 + br2 ----
    "v_mov_b32 v74, %[bi2]\n\t"
    "v_mov_b32 v75, 0\n\t"
    "v_mov_b32 v78, %[br2]\n\t"
    "v_mov_b32 v79, 0\n\t"
    "v_pk_fma_f32 v[74:75], s[20:21], v[30:31], v[74:75]\n\t"
    "v_pk_fma_f32 v[78:79], s[40:41], v[50:51], v[78:79]\n\t"
    "v_pk_fma_f32 v[74:75], s[22:23], v[32:33], v[74:75]\n\t"
    "v_pk_fma_f32 v[78:79], s[42:43], v[52:53], v[78:79]\n\t"
    "v_pk_fma_f32 v[74:75], s[24:25], v[34:35], v[74:75]\n\t"
    "v_pk_fma_f32 v[78:79], s[44:45], v[54:55], v[78:79]\n\t"
    "v_pk_fma_f32 v[74:75], s[26:27], v[36:37], v[74:75]\n\t"
    "v_pk_fma_f32 v[78:79], s[46:47], v[56:57], v[78:79]\n\t"
    "v_pk_fma_f32 v[74:75], s[28:29], v[38:39], v[74:75]\n\t"
    "v_pk_fma_f32 v[78:79], s[48:49], v[58:59], v[78:79]\n\t"
    "v_pk_fma_f32 v[74:75], s[30:31], v[40:41], v[74:75]\n\t"
    "v_pk_fma_f32 v[78:79], s[50:51], v[60:61], v[78:79]\n\t"
    "v_pk_fma_f32 v[74:75], s[32:33], v[42:43], v[74:75]\n\t"
    "v_pk_fma_f32 v[78:79], s[52:53], v[62:63], v[78:79]\n\t"
    "v_pk_fma_f32 v[74:75], s[34:35], v[44:45], v[74:75]\n\t"
    "v_pk_fma_f32 v[78:79], s[54:55], v[64:65], v[78:79]\n\t"
    "v_pk_fma_f32 v[74:75], s[36:37], v[46:47], v[74:75]\n\t"
    "v_pk_fma_f32 v[78:79], s[56:57], v[66:67], v[78:79]\n\t"
    "v_pk_fma_f32 v[74:75], s[38:39], v[48:49], v[74:75]\n\t"
    "v_pk_fma_f32 v[78:79], s[58:59], v[68:69], v[78:79]\n\t"
    "v_add_f32 v74, v74, v75\n\t"          // m2
    "v_add_f32 v78, v78, v79\n\t"          // n2
    // gates layer 2
    "v_add_f32 v75, v74, v78\n\t"
    "v_mul_f32 v75, 0xbfb8aa3b, v75\n\t"
    "v_exp_f32 v75, v75\n\t"
    "s_nop 1\n\t"                          // TRANS result hazard fence
    "v_add_f32 v75, 1.0, v75\n\t"
    "v_rcp_f32 v75, v75\n\t"
    "s_nop 1\n\t"                          // TRANS result hazard fence
    "ds_bpermute_b32 v76, %[a1], v75\n\t"
    "s_waitcnt lgkmcnt(0)\n\t"
    "v_fma_f32 v77, v76, v78, v74\n\t"     // hp2 = rr2*n2 + m2
    "v_mul_f32 v77, 0x4038aa3b, v77\n\t"
    "v_exp_f32 v77, v77\n\t"
    "s_nop 1\n\t"                          // TRANS result hazard fence
    "v_add_f32 v77, 1.0, v77\n\t"
    "v_rcp_f32 v77, v77\n\t"
    "s_nop 1\n\t"                          // TRANS result hazard fence
    "v_fma_f32 v77, -2.0, v77, 1.0\n\t"
    "ds_bpermute_b32 v76, %[a2], v77\n\t"
    "s_waitcnt lgkmcnt(0)\n\t"
    "v_sub_f32 v79, v71, v76\n\t"
    "v_fma_f32 v71, v75, v79, v76\n\t"     // h2 = g2*(h2-hv2)+hv2
    "s_nop 1\n\t"                          // VALU->readlane fence
    L2FMA(40,0) L2FMA(41,1) L2FMA(42,2) L2FMA(43,3) L2FMA(44,4)
    L2FMA(45,5) L2FMA(46,6) L2FMA(47,7) L2FMA(48,8) L2FMA(49,9)
    L2FMA(50,10) L2FMA(51,11) L2FMA(52,12) L2FMA(53,13) L2FMA(54,14)
    L2FMA(55,15) L2FMA(56,16) L2FMA(57,17) L2FMA(58,18) L2FMA(59,19)
    "s_sub_u32 s67, s67, 1\n\t"
    "s_cmp_lg_u32 s67, 0\n\t"
    "s_cbranch_scc1 0b\n\t"
    "s_waitcnt vmcnt(0) lgkmcnt(0)\n\t"    // drain before regs return to RA
    "v_mov_b32 %[h2o], v71\n\t"
    : [h2o] "=v"(h2out)
    : [wsp] "s"(ws), [xp] "s"(xr), [tabp] "s"(tab),
      [o1] "v"(o1), [o2] "v"(o2), [o3] "v"(o3), [jc4] "v"(jc4),
      [a1] "v"(a1), [a2] "v"(a2),
      [br1] "v"(br1), [bi2] "v"(bi2), [br2] "v"(br2)
    : "memory", "vcc", "scc",
      "v10","v11","v12","v13","v14","v15","v16","v17","v18","v19",
      "v20","v21","v22","v23","v24","v25","v26","v27","v28","v29",
      "v30","v31","v32","v33","v34","v35","v36","v37","v38","v39",
      "v40","v41","v42","v43","v44","v45","v46","v47","v48","v49",
      "v50","v51","v52","v53","v54","v55","v56","v57","v58","v59",
      "v60","v61","v62","v63","v64","v65","v66","v67","v68","v69",
      "v70","v71","v72","v73","v74","v75","v76","v77","v78","v79","v80",
      "s20","s21","s22","s23","s24","s25","s26","s27","s28","s29",
      "s30","s31","s32","s33","s34","s35","s36","s37","s38","s39",
      "s40","s41","s42","s43","s44","s45","s46","s47","s48","s49",
      "s50","s51","s52","s53","s54","s55","s56","s57","s58","s59",
      "s64","s65","s66","s67");
#undef L1FMA
#undef L2FMA

  // ---- dense: logits = h2 @ Wd + bd ----
  if (j < 15) {
    float a = ws[OFF_BD + j];
#pragma unroll
    for (int k = 0; k < HID; ++k)
      a = fmaf(rdl(h2out, k), ws[OFF_WD + k * 15 + j], a);
    if (isf) ((float*)out)[(size_t)e * 15 + j] = a;
    else ((__hip_bfloat16*)out)[(size_t)e * 15 + j] = __float2bfloat16(a);
  }
}

extern "C" void kernel_launch(void* const* d_in, const int* in_sizes, int n_in,
                              void* d_out, int out_size, void* d_ws, size_t ws_size,
                              hipStream_t stream) {
  const int* x    = (const int*)d_in[0];
  const void* emb = d_in[1];
  const void* W1  = d_in[2];
  const void* U1  = d_in[3];
  const void* b1  = d_in[4];
  const void* W2  = d_in[5];
  const void* U2  = d_in[6];
  const void* b2  = d_in[7];
  const void* Wd  = d_in[8];
  const void* bd  = d_in[9];
  float* ws = (float*)d_ws;   // 12,016,640 B used (rounds 7/8/11/12 proven safe)

  build_table<<<BBLK, 256, 0, stream>>>(
      emb, W1, b1, U1, W2, U2, b2, Wd, bd, ws);
  gru_main<<<8192, 64, 0, stream>>>(x, ws, emb, d_out);
}

// Round 14
// 241.869 us; speedup vs baseline: 1.1182x; 1.1182x over previous
//
#include <hip/hip_runtime.h>
#include <hip/hip_bf16.h>
#include <hip/hip_fp16.h>

#define SEQ_T 100
#define HID 20
#define EMB_D 50
#define VOCAB_N 50000
#define TABW 60          // tab row stride (floats) = 60 gate cols [z20|r20|h20]
#define NTILE 3125       // VOCAB_N/16
#define BBLK 200         // build_table blocks (x4 waves = 800 waves)

typedef short sh8 __attribute__((ext_vector_type(8)));   // 8 bf16 bit patterns
typedef float f4  __attribute__((ext_vector_type(4)));

// ws layout (float/dword offsets). TOTAL footprint unchanged: 12,016,640 B.
// U1/W2/U2 now stored as PACKED f16 k-pairs (bf16 source -> f16 is EXACT):
// per column j: 10 dwords, each {f16 w[2p][j] lo, f16 w[2p+1][j] hi}.
#define OFF_U1P 0        // 600 dwords (60 cols x 10 pairs)
#define OFF_W2P 600
#define OFF_U2P 1200
#define OFF_B1  3600     // 120 fp32
#define OFF_B2  3720     // 120 fp32
#define OFF_WD  3840     // 300 fp32
#define OFF_BD  4140     // 15 fp32
#define OFF_TAB 4160     // 50000*60 fp32

__device__ __forceinline__ float ldf(const void* p, int i, int isf) {
  return isf ? ((const float*)p)[i]
             : __bfloat162float(((const __hip_bfloat16*)p)[i]);
}
__device__ __forceinline__ short f2bf(float f) {   // RNE fp32->bf16 bits
  unsigned u = __float_as_uint(f);
  u += 0x7fffu + ((u >> 16) & 1u);
  return (short)(u >> 16);
}
__device__ __forceinline__ float rdl(float v, int l) {
  return __uint_as_float(__builtin_amdgcn_readlane(__float_as_uint(v), l));
}
// fp32 data read as u16 halfwords has uniform-random bf16-exponent fields
// (>=140 w.p. ~0.45 per low half); bf16 N(0,0.05) never exceeds ~125.
__device__ __forceinline__ int detect_isf(const void* emb) {
  uint4 dv = ((const uint4*)emb)[threadIdx.x & 63];
  int big = 0;
#pragma unroll
  for (int i = 0; i < 4; ++i) {
    unsigned w = ((const unsigned*)&dv)[i];
    big |= (((w >> 7) & 0xFF) >= 140) | (((w >> 23) & 0xFF) >= 140);
  }
  return (__ballot(big) != 0ull) ? 1 : 0;
}

// tab = emb @ W1 + bi1 on the matrix cores (round-13 structure, verified).
// Block 0 preps: packed-f16 transposed U1/W2/U2 + fp32 biases/Wd/bd.
__global__ __launch_bounds__(256) void build_table(
    const void* __restrict__ emb, const void* __restrict__ W1,
    const void* __restrict__ b1,
    const void* __restrict__ U1, const void* __restrict__ W2,
    const void* __restrict__ U2, const void* __restrict__ b2,
    const void* __restrict__ Wd, const void* __restrict__ bd,
    float* __restrict__ ws)
{
  const int isf = detect_isf(emb);
  if (blockIdx.x == 0) {                     // fold: weight prep
    const int t = threadIdx.x;
    unsigned* wsu = (unsigned*)ws;
    for (int i = t; i < 600; i += 256) {     // packed f16 k-pairs, transposed
      const int j = i / 10, p = i % 10;
      const int k0 = 2 * p, k1 = 2 * p + 1;
#define PK(M) ((unsigned)__half_as_ushort(__float2half_rn(ldf(M, k0 * 60 + j, isf))) | \
               ((unsigned)__half_as_ushort(__float2half_rn(ldf(M, k1 * 60 + j, isf))) << 16))
      wsu[OFF_U1P + i] = PK(U1);
      wsu[OFF_W2P + i] = PK(W2);
      wsu[OFF_U2P + i] = PK(U2);
#undef PK
    }
    for (int i = t; i < 120; i += 256) {
      ws[OFF_B1 + i] = ldf(b1, i, isf);
      ws[OFF_B2 + i] = ldf(b2, i, isf);
    }
    for (int i = t; i < 300; i += 256) ws[OFF_WD + i] = ldf(Wd, i, isf);
    for (int i = t; i < 15;  i += 256) ws[OFF_BD + i] = ldf(bd, i, isf);
  }

  const int L = threadIdx.x & 63, q = L >> 4, c = L & 15;
  const int wid = blockIdx.x * 4 + (threadIdx.x >> 6);
  float* __restrict__ tab = ws + OFF_TAB;

  __shared__ int4 sB[64][8];                 // B-frags built once per block
  if (threadIdx.x < 64) {
#pragma unroll
    for (int nt = 0; nt < 4; ++nt) {
      const int col = nt * 16 + c;
      sh8 B0, B1;
#pragma unroll
      for (int jj = 0; jj < 8; ++jj) {       // B[k=quad*8+j][n=lane&15]
        const int k0 = q * 8 + jj, k1 = 32 + q * 8 + jj;
        B0[jj] = (col < TABW) ? f2bf(ldf(W1, k0 * TABW + col, isf)) : (short)0;
        B1[jj] = (col < TABW && k1 < EMB_D)
                     ? f2bf(ldf(W1, k1 * TABW + col, isf)) : (short)0;
      }
      sB[L][nt * 2]     = *(const int4*)&B0;
      sB[L][nt * 2 + 1] = *(const int4*)&B1;
    }
  }
  float bi[4];
#pragma unroll
  for (int nt = 0; nt < 4; ++nt) {
    const int col = nt * 16 + c;
    bi[nt] = (col < TABW) ? ldf(b1, col, isf) : 0.f;
  }
  __syncthreads();

  for (int tile = wid; tile < NTILE; tile += BBLK * 4) {
    const int v0 = tile * 16;
    sh8 A0, A1;
#pragma unroll
    for (int jj = 0; jj < 8; ++jj) { A0[jj] = 0; A1[jj] = 0; }
    if (!isf) {
      const unsigned short* eb = (const unsigned short*)emb;
      const size_t rb = (size_t)(v0 + c) * EMB_D;
#pragma unroll
      for (int i = 0; i < 4; ++i) {          // dword loads: rows are 100 B
        unsigned d = *(const unsigned*)(eb + rb + q * 8 + 2 * i);
        A0[2 * i] = (short)(d & 0xffff); A0[2 * i + 1] = (short)(d >> 16);
      }
      const int k1b = 32 + q * 8;
#pragma unroll
      for (int i = 0; i < 4; ++i) {
        const int k = k1b + 2 * i;
        if (k + 1 < EMB_D) {
          unsigned d = *(const unsigned*)(eb + rb + k);
          A1[2 * i] = (short)(d & 0xffff); A1[2 * i + 1] = (short)(d >> 16);
        }
      }
    } else {
      const float* ef = (const float*)emb;
      const size_t rb = (size_t)(v0 + c) * EMB_D;
#pragma unroll
      for (int jj = 0; jj < 8; ++jj) {
        const int k0 = q * 8 + jj, k1 = 32 + q * 8 + jj;
        A0[jj] = f2bf(ef[rb + k0]);
        A1[jj] = (k1 < EMB_D) ? f2bf(ef[rb + k1]) : (short)0;
      }
    }
#pragma unroll
    for (int nt = 0; nt < 4; ++nt) {
      int4 b0i = sB[L][nt * 2], b1i = sB[L][nt * 2 + 1];
      sh8 B0 = *(const sh8*)&b0i, B1 = *(const sh8*)&b1i;
      const int col = nt * 16 + c;
      f4 acc = { bi[nt], bi[nt], bi[nt], bi[nt] };
      acc = __builtin_amdgcn_mfma_f32_16x16x32_bf16(A0, B0, acc, 0, 0, 0);
      acc = __builtin_amdgcn_mfma_f32_16x16x32_bf16(A1, B1, acc, 0, 0, 0);
      if (col < TABW) {
#pragma unroll
        for (int r = 0; r < 4; ++r)
          tab[(size_t)(v0 + q * 4 + r) * TABW + col] = acc[r];
      }
    }
  }
}

// ONE batch element per wave; full 100-step GRU loop in inline asm.
// ROUND-14: matvecs via v_dot2_f32_f16 (2 MACs/lane/instr, f16 pairs in
// SGPR h x VGPR weights; bf16 source -> f16 conversion EXACT). h masters
// stay fp32 (v40/v41); broadcast packs pairs via cvt+swizzle+pack ->
// 10 readlanes/layer (was 20). 30 weight VGPRs -> ~52 total -> 8 waves/SIMD.
__global__ __launch_bounds__(64, 8) void gru_main(
    const int* __restrict__ x, const float* __restrict__ ws,
    const void* __restrict__ emb, void* __restrict__ out)
{
  const int isf = detect_isf(emb);   // output dtype only
  const int j = threadIdx.x & 63;
  const int e = blockIdx.x;
  const int jc = j < TABW ? j : 0;

  const int* xr = x + (size_t)e * SEQ_T;
  const float* tab = ws + OFF_TAB;
  const int o1 = jc * 40;                    // 10 packed dwords per column
  const int jc4 = jc * 4;                    // byte offset of col jc in tab row
  const int a1 = ((j - 20) & 63) * 4;        // bpermute addr: r -> h-lanes
  const int a2 = ((j + 40) & 63) * 4;        // bpermute addr: hc -> z-lanes
  const float br1 = ws[OFF_B1 + 60 + jc];
  const float bi2 = ws[OFF_B2 + jc];
  const float br2 = ws[OFF_B2 + 60 + jc];
  float h2out;

  asm volatile(
    // ---- packed f16 weights: U1P v10-19, W2P v20-29, U2P v30-39 ----
    "global_load_dwordx4 v[10:13], %[o1], %[wsp] offset:0\n\t"
    "global_load_dwordx4 v[14:17], %[o1], %[wsp] offset:16\n\t"
    "global_load_dwordx2 v[18:19], %[o1], %[wsp] offset:32\n\t"
    "v_add_u32 v44, 0x960, %[o1]\n\t"        // +2400 B -> W2P
    "v_add_u32 v45, 0x12c0, %[o1]\n\t"       // +4800 B -> U2P
    "global_load_dwordx4 v[20:23], v44, %[wsp] offset:0\n\t"
    "global_load_dwordx4 v[24:27], v44, %[wsp] offset:16\n\t"
    "global_load_dwordx2 v[28:29], v44, %[wsp] offset:32\n\t"
    "global_load_dwordx4 v[30:33], v45, %[wsp] offset:0\n\t"
    "global_load_dwordx4 v[34:37], v45, %[wsp] offset:16\n\t"
    "global_load_dwordx2 v[38:39], v45, %[wsp] offset:32\n\t"
    // ---- h state: packed f16 pairs s20-29 (h1), s30-39 (h2); masters v40/41
    "s_mov_b64 s[20:21], 0\n\ts_mov_b64 s[22:23], 0\n\t"
    "s_mov_b64 s[24:25], 0\n\ts_mov_b64 s[26:27], 0\n\t"
    "s_mov_b64 s[28:29], 0\n\t"
    "s_mov_b64 s[30:31], 0\n\ts_mov_b64 s[32:33], 0\n\t"
    "s_mov_b64 s[34:35], 0\n\ts_mov_b64 s[36:37], 0\n\t"
    "s_mov_b64 s[38:39], 0\n\t"
    "v_mov_b32 v40, 0\n\t"
    "v_mov_b32 v41, 0\n\t"
    // ---- prime mx(0), mx(1); idx(2) in flight. row stride 240 B ----
    "s_load_dword s65, %[xp], 0x0\n\t"
    "s_load_dword s66, %[xp], 0x4\n\t"
    "s_waitcnt lgkmcnt(0)\n\t"
    "s_mul_i32 s65, s65, 240\n\t"
    "s_mul_i32 s66, s66, 240\n\t"
    "v_add_u32 v50, s65, %[jc4]\n\t"
    "global_load_dword v42, v50, %[tabp]\n\t"
    "v_add_u32 v50, s66, %[jc4]\n\t"
    "global_load_dword v43, v50, %[tabp]\n\t"
    "s_load_dword s65, %[xp], 0x8\n\t"
    "s_movk_i32 s64, 0xc\n\t"
    "s_movk_i32 s67, 0x64\n\t"
    "s_waitcnt vmcnt(0)\n\t"
    "0:\n\t"
    // ---- layer 1: mh = h1 @ U1 + br1 (10 f16-pair dots) ----
    "v_mov_b32 v44, %[br1]\n\t"
    "v_dot2_f32_f16 v44, s20, v10, v44\n\t"
    "v_dot2_f32_f16 v44, s21, v11, v44\n\t"
    "v_dot2_f32_f16 v44, s22, v12, v44\n\t"
    "v_dot2_f32_f16 v44, s23, v13, v44\n\t"
    "v_dot2_f32_f16 v44, s24, v14, v44\n\t"
    "v_dot2_f32_f16 v44, s25, v15, v44\n\t"
    "v_dot2_f32_f16 v44, s26, v16, v44\n\t"
    "v_dot2_f32_f16 v44, s27, v17, v44\n\t"
    "v_dot2_f32_f16 v44, s28, v18, v44\n\t"
    "v_dot2_f32_f16 v44, s29, v19, v44\n\t"
    // g = sigmoid(mx + mh)   (z in lanes 0..19, r in 20..39)
    "v_add_f32 v45, v42, v44\n\t"
    "v_mul_f32 v45, 0xbfb8aa3b, v45\n\t"   // * -log2(e)
    "v_exp_f32 v45, v45\n\t"
    "s_nop 1\n\t"                          // TRANS result hazard fence
    "v_add_f32 v45, 1.0, v45\n\t"
    "v_rcp_f32 v45, v45\n\t"
    "s_nop 1\n\t"
    "ds_bpermute_b32 v46, %[a1], v45\n\t"  // rr: h-lanes pull r
    "s_waitcnt lgkmcnt(0)\n\t"
    "v_fma_f32 v47, v46, v44, v42\n\t"     // hp = rr*mh + mx
    "v_mul_f32 v47, 0x4038aa3b, v47\n\t"   // * 2*log2(e)
    "v_exp_f32 v47, v47\n\t"
    "s_nop 1\n\t"
    "v_add_f32 v47, 1.0, v47\n\t"
    "v_rcp_f32 v47, v47\n\t"
    "s_nop 1\n\t"
    "v_fma_f32 v47, -2.0, v47, 1.0\n\t"    // hc = tanh(hp)
    "ds_bpermute_b32 v46, %[a2], v47\n\t"  // hv: z-lanes pull hc
    "s_waitcnt lgkmcnt(0)\n\t"
    "v_sub_f32 v48, v40, v46\n\t"
    "v_fma_f32 v40, v45, v48, v46\n\t"     // h1 master = g*(h1-hv)+hv
    "s_nop 1\n\t"
    // pack h1 pairs -> f16x2, broadcast to s20-29 (10 readlanes)
    "v_cvt_f16_f32 v46, v40\n\t"
    "s_nop 1\n\t"
    "ds_swizzle_b32 v47, v46 offset:0x041F\n\t"  // xor lane^1
    "s_waitcnt lgkmcnt(0)\n\t"
    "v_pack_b32_f16 v46, v46, v47\n\t"     // {own lo, neighbor hi}
    "s_nop 1\n\t"
    "v_readlane_b32 s20, v46, 0\n\t"
    "v_readlane_b32 s21, v46, 2\n\t"
    "v_readlane_b32 s22, v46, 4\n\t"
    "v_readlane_b32 s23, v46, 6\n\t"
    "v_readlane_b32 s24, v46, 8\n\t"
    "v_readlane_b32 s25, v46, 10\n\t"
    "v_readlane_b32 s26, v46, 12\n\t"
    "v_readlane_b32 s27, v46, 14\n\t"
    "v_readlane_b32 s28, v46, 16\n\t"
    "v_readlane_b32 s29, v46, 18\n\t"
    // ---- rotate mx pipeline, prefetch mx(t+2), idx(t+3) ----
    "s_mul_i32 s66, s65, 240\n\t"
    "v_add_u32 v50, s66, %[jc4]\n\t"
    "s_waitcnt vmcnt(0)\n\t"
    "v_mov_b32 v42, v43\n\t"
    "global_load_dword v43, v50, %[tabp]\n\t"
    "s_min_u32 s64, s64, 396\n\t"
    "s_load_dword s65, %[xp], s64\n\t"
    "s_add_u32 s64, s64, 4\n\t"
    // ---- layer 2: m2 = h1new @ W2 + bi2 ; n2 = h2 @ U2 + br2 ----
    "v_mov_b32 v44, %[bi2]\n\t"
    "v_mov_b32 v48, %[br2]\n\t"
    "v_dot2_f32_f16 v44, s20, v20, v44\n\t"
    "v_dot2_f32_f16 v48, s30, v30, v48\n\t"
    "v_dot2_f32_f16 v44, s21, v21, v44\n\t"
    "v_dot2_f32_f16 v48, s31, v31, v48\n\t"
    "v_dot2_f32_f16 v44, s22, v22, v44\n\t"
    "v_dot2_f32_f16 v48, s32, v32, v48\n\t"
    "v_dot2_f32_f16 v44, s23, v23, v44\n\t"
    "v_dot2_f32_f16 v48, s33, v33, v48\n\t"
    "v_dot2_f32_f16 v44, s24, v24, v44\n\t"
    "v_dot2_f32_f16 v48, s34, v34, v48\n\t"
    "v_dot2_f32_f16 v44, s25, v25, v44\n\t"
    "v_dot2_f32_f16 v48, s35, v35, v48\n\t"
    "v_dot2_f32_f16 v44, s26, v26, v44\n\t"
    "v_dot2_f32_f16 v48, s36, v36, v48\n\t"
    "v_dot2_f32_f16 v44, s27, v27, v44\n\t"
    "v_dot2_f32_f16 v48, s37, v37, v48\n\t"
    "v_dot2_f32_f16 v44, s28, v28, v44\n\t"
    "v_dot2_f32_f16 v48, s38, v38, v48\n\t"
    "v_dot2_f32_f16 v44, s29, v29, v44\n\t"
    "v_dot2_f32_f16 v48, s39, v39, v48\n\t"
    // gates layer 2
    "v_add_f32 v45, v44, v48\n\t"
    "v_mul_f32 v45, 0xbfb8aa3b, v45\n\t"
    "v_exp_f32 v45, v45\n\t"
    "s_nop 1\n\t"
    "v_add_f32 v45, 1.0, v45\n\t"
    "v_rcp_f32 v45, v45\n\t"
    "s_nop 1\n\t"
    "ds_bpermute_b32 v46, %[a1], v45\n\t"
    "s_waitcnt lgkmcnt(0)\n\t"
    "v_fma_f32 v47, v46, v48, v44\n\t"     // hp2 = rr2*n2 + m2
    "v_mul_f32 v47, 0x4038aa3b, v47\n\t"
    "v_exp_f32 v47, v47\n\t"
    "s_nop 1\n\t"
    "v_add_f32 v47, 1.0, v47\n\t"
    "v_rcp_f32 v47, v47\n\t"
    "s_nop 1\n\t"
    "v_fma_f32 v47, -2.0, v47, 1.0\n\t"
    "ds_bpermute_b32 v46, %[a2], v47\n\t"
    "s_waitcnt lgkmcnt(0)\n\t"
    "v_sub_f32 v49, v41, v46\n\t"
    "v_fma_f32 v41, v45, v49, v46\n\t"     // h2 master
    "s_nop 1\n\t"
    "v_cvt_f16_f32 v46, v41\n\t"
    "s_nop 1\n\t"
    "ds_swizzle_b32 v47, v46 offset:0x041F\n\t"
    "s_waitcnt lgkmcnt(0)\n\t"
    "v_pack_b32_f16 v46, v46, v47\n\t"
    "s_nop 1\n\t"
    "v_readlane_b32 s30, v46, 0\n\t"
    "v_readlane_b32 s31, v46, 2\n\t"
    "v_readlane_b32 s32, v46, 4\n\t"
    "v_readlane_b32 s33, v46, 6\n\t"
    "v_readlane_b32 s34, v46, 8\n\t"
    "v_readlane_b32 s35, v46, 10\n\t"
    "v_readlane_b32 s36, v46, 12\n\t"
    "v_readlane_b32 s37, v46, 14\n\t"
    "v_readlane_b32 s38, v46, 16\n\t"
    "v_readlane_b32 s39, v46, 18\n\t"
    "s_sub_u32 s67, s67, 1\n\t"
    "s_cmp_lg_u32 s67, 0\n\t"
    "s_cbranch_scc1 0b\n\t"
    "s_waitcnt vmcnt(0) lgkmcnt(0)\n\t"
    "v_mov_b32 %[h2o], v41\n\t"
    : [h2o] "=v"(h2out)
    : [wsp] "s"(ws), [xp] "s"(xr), [tabp] "s"(tab),
      [o1] "v"(o1), [jc4] "v"(jc4), [a1] "v"(a1), [a2] "v"(a2),
      [br1] "v"(br1), [bi2] "v"(bi2), [br2] "v"(br2)
    : "memory", "vcc", "scc",
      "v10","v11","v12","v13","v14","v15","v16","v17","v18","v19",
      "v20","v21","v22","v23","v24","v25","v26","v27","v28","v29",
      "v30","v31","v32","v33","v34","v35","v36","v37","v38","v39",
      "v40","v41","v42","v43","v44","v45","v46","v47","v48","v49","v50",
      "s20","s21","s22","s23","s24","s25","s26","s27","s28","s29",
      "s30","s31","s32","s33","s34","s35","s36","s37","s38","s39",
      "s64","s65","s66","s67");

  // ---- dense: logits = h2 @ Wd + bd (h2 master fp32 in h2out lanes 0..19) ----
  if (j < 15) {
    float a = ws[OFF_BD + j];
#pragma unroll
    for (int k = 0; k < HID; ++k)
      a = fmaf(rdl(h2out, k), ws[OFF_WD + k * 15 + j], a);
    if (isf) ((float*)out)[(size_t)e * 15 + j] = a;
    else ((__hip_bfloat16*)out)[(size_t)e * 15 + j] = __float2bfloat16(a);
  }
}

extern "C" void kernel_launch(void* const* d_in, const int* in_sizes, int n_in,
                              void* d_out, int out_size, void* d_ws, size_t ws_size,
                              hipStream_t stream) {
  const int* x    = (const int*)d_in[0];
  const void* emb = d_in[1];
  const void* W1  = d_in[2];
  const void* U1  = d_in[3];
  const void* b1  = d_in[4];
  const void* W2  = d_in[5];
  const void* U2  = d_in[6];
  const void* b2  = d_in[7];
  const void* Wd  = d_in[8];
  const void* bd  = d_in[9];
  float* ws = (float*)d_ws;   // 12,016,640 B used (proven safe)

  build_table<<<BBLK, 256, 0, stream>>>(
      emb, W1, b1, U1, W2, U2, b2, Wd, bd, ws);
  gru_main<<<8192, 64, 0, stream>>>(x, ws, emb, d_out);
}